// Round 1
// 2673.900 us; speedup vs baseline: 1.0647x; 1.0647x over previous
//
#include <hip/hip_runtime.h>
#include <hip/hip_bf16.h>
#include <cmath>

using bf16 = __hip_bfloat16;
typedef short bf16x8 __attribute__((ext_vector_type(8)));
typedef float f32x4 __attribute__((ext_vector_type(4)));

#define GLD_LDS16(g, l) __builtin_amdgcn_global_load_lds( \
    (const __attribute__((address_space(1))) void*)(g),   \
    (__attribute__((address_space(3))) void*)(l), 16, 0, 0)

#define MFMA16(a,b,c) __builtin_amdgcn_mfma_f32_16x16x32_bf16((a),(b),(c),0,0,0)

// problem constants
#define C_SP 800
#define C_SS 48
#define C_B  8
#define C_N  848      // SP+SS
#define C_NP 864      // padded to 27*32
#define C_DP 2048
#define C_DS 1024
#define C_H  8
#define C_HD 256
#define C_FP 16384
#define C_FS 4096

__device__ inline float wredsum(float v){
  #pragma unroll
  for (int o = 32; o > 0; o >>= 1) v += __shfl_down(v, o, 64);
  return v;
}
__device__ inline float wredmax(float v){
  #pragma unroll
  for (int o = 32; o > 0; o >>= 1) v = fmaxf(v, __shfl_down(v, o, 64));
  return v;
}

// Two-level locality swizzle
__device__ inline void tile_swizzle(int lin, int nmt, int nnt, int& tm, int& tn){
  int total = nmt * nnt;
  int t;
  if ((total & 7) == 0) t = (lin & 7) * (total >> 3) + (lin >> 3);
  else t = lin;
  const int GN = 8;
  int band = GN * nmt;
  int g = t / band;
  int n0 = g * GN;
  int gw = nnt - n0; if (gw > GN) gw = GN;
  int r = t - g * band;
  tm = r / gw;
  tn = n0 + r % gw;
}

// ---------------- fused fp32 -> bf16 weight conversion (single launch) ----------------
struct ConvTab {
  const float* src[14];
  bf16* dst[14];
  int cum[15];   // cumulative block counts; each block = 2048 elements
};
__global__ void convert_all_k(ConvTab t){
  int b = blockIdx.x;
  int s = 0;
  #pragma unroll 1
  while (b >= t.cum[s+1]) ++s;
  long i = ((long)(b - t.cum[s]) * 256 + threadIdx.x) * 8;
  const float* src = t.src[s] + i;
  float4 v0 = *(const float4*)(src);
  float4 v1 = *(const float4*)(src + 4);
  bf16 o[8];
  o[0]=__float2bfloat16(v0.x); o[1]=__float2bfloat16(v0.y);
  o[2]=__float2bfloat16(v0.z); o[3]=__float2bfloat16(v0.w);
  o[4]=__float2bfloat16(v1.x); o[5]=__float2bfloat16(v1.y);
  o[6]=__float2bfloat16(v1.z); o[7]=__float2bfloat16(v1.w);
  *(int4*)(t.dst[s] + i) = *(const int4*)o;
}

// ---------------- gemma RMS norm (D=2048) -> bf16 ----------------
__global__ void gemma_norm_k(const float* __restrict__ x, const float* __restrict__ w,
                             bf16* __restrict__ out){
  int row = blockIdx.x;
  int tid = threadIdx.x;
  const float* xr = x + (long)row * C_DP;
  float4 v0 = *(const float4*)(xr + tid*4);
  float4 v1 = *(const float4*)(xr + 1024 + tid*4);
  float ss = v0.x*v0.x + v0.y*v0.y + v0.z*v0.z + v0.w*v0.w
           + v1.x*v1.x + v1.y*v1.y + v1.z*v1.z + v1.w*v1.w;
  ss = wredsum(ss);
  __shared__ float red[4];
  if ((tid & 63) == 0) red[tid >> 6] = ss;
  __syncthreads();
  float tot = red[0] + red[1] + red[2] + red[3];
  float rs = rsqrtf(tot * (1.0f/2048.0f) + 1e-6f);
  bf16* orow = out + (long)row * C_DP;
  const float* wv = w;
  #pragma unroll
  for (int j = 0; j < 4; ++j){
    int c0 = tid*4 + j;
    orow[c0]        = __float2bfloat16(((&v0.x)[j]) * rs * (1.0f + wv[c0]));
    orow[c0 + 1024] = __float2bfloat16(((&v1.x)[j]) * rs * (1.0f + wv[c0 + 1024]));
  }
}

// ---------------- ada modulation: mod = cond @ w^T + b (both layers) ----------------
__global__ void ada_mod_k(const float* __restrict__ cond,
                          const float* __restrict__ w1, const float* __restrict__ b1,
                          const float* __restrict__ w2, const float* __restrict__ b2,
                          float* __restrict__ mod1, float* __restrict__ mod2){
  int idx = blockIdx.x * 256 + threadIdx.x;   // 2*3072 outputs
  int sel = idx / 3072, col = idx - sel * 3072;
  const float* w = (sel ? w2 : w1) + (long)col * C_DS;
  float acc[8] = {0,0,0,0,0,0,0,0};
  for (int k = 0; k < C_DS; k += 4){
    float4 wv = *(const float4*)(w + k);
    #pragma unroll
    for (int b = 0; b < 8; ++b){
      float4 cv = *(const float4*)(cond + b*C_DS + k);
      acc[b] += wv.x*cv.x + wv.y*cv.y + wv.z*cv.z + wv.w*cv.w;
    }
  }
  float bias = (sel ? b2 : b1)[col];
  float* m = sel ? mod2 : mod1;
  #pragma unroll
  for (int b = 0; b < 8; ++b) m[b*3072 + col] = acc[b] + bias;
}

// ---------------- ada norm (D=1024): rms(x)*(1+scale)+shift -> bf16 ----------------
__global__ void ada_norm_k(const float* __restrict__ x, const float* __restrict__ mod,
                           bf16* __restrict__ out){
  int row = blockIdx.x;       // 0..383
  int b = row / C_SS;
  int tid = threadIdx.x;
  const float* xr = x + (long)row * C_DS;
  float4 v = *(const float4*)(xr + tid*4);
  float ss = v.x*v.x + v.y*v.y + v.z*v.z + v.w*v.w;
  ss = wredsum(ss);
  __shared__ float red[4];
  if ((tid & 63) == 0) red[tid >> 6] = ss;
  __syncthreads();
  float tot = red[0] + red[1] + red[2] + red[3];
  float rs = rsqrtf(tot * (1.0f/1024.0f) + 1e-6f);
  const float* mrow = mod + (long)b * 3072;
  bf16* orow = out + (long)row * C_DS;
  #pragma unroll
  for (int j = 0; j < 4; ++j){
    int col = tid*4 + j;
    float val = ((&v.x)[j]) * rs * (1.0f + mrow[col]) + mrow[1024 + col];
    orow[col] = __float2bfloat16(val);
  }
}

// ---------------- RoPE + layout scatter ----------------
__global__ void rope_k(const float* __restrict__ qkv_p, const float* __restrict__ qkv_s,
                       bf16* __restrict__ q_r, bf16* __restrict__ k_r, bf16* __restrict__ v_t){
  int bn = blockIdx.x;
  int b = bn / C_N, n = bn - b * C_N;
  int d = threadIdx.x;  // 0..255
  const float* src = (n < C_SP) ? (qkv_p + ((long)b*C_SP + n) * 2560)
                                : (qkv_s + ((long)b*C_SS + (n - C_SP)) * 2560);
  int i = d & 127;
  float inv = expf(-(float)i * (9.210340371976184f / 128.0f)); // 1/10000^(i/128)
  float fr = (float)n * inv;
  float sn, cs;
  sincosf(fr, &sn, &cs);
  bool lo = d < 128;
  int dpair = lo ? d + 128 : d - 128;
  #pragma unroll
  for (int h = 0; h < C_H; ++h){
    float a = src[h*C_HD + d], o = src[h*C_HD + dpair];
    float r = lo ? (a*cs - o*sn) : (a*cs + o*sn);
    q_r[(((long)b*C_H + h)*C_N + n)*C_HD + d] = __float2bfloat16(r);
  }
  {
    float a = src[2048 + d], o = src[2048 + dpair];
    float r = lo ? (a*cs - o*sn) : (a*cs + o*sn);
    k_r[((long)b*C_N + n)*C_HD + d] = __float2bfloat16(r);
  }
  v_t[((long)b*C_HD + d)*C_NP + n] = __float2bfloat16(src[2304 + d]);
  if (n < C_NP - C_N)   // zero K-padding columns 848..863
    v_t[((long)b*C_HD + d)*C_NP + C_N + n] = __float2bfloat16(0.0f);
}

// ---------------- masked softmax over S rows (bf16 in/out, fp32 math) ----------------
__global__ void softmax_k(bf16* __restrict__ S){
  int m = blockIdx.x;        // 0..6783 (= h*848 + qn)
  int b = blockIdx.y;
  int qn = m % C_N;
  bf16* row = S + ((long)b * (C_H*C_N) + m) * C_NP;
  int tid = threadIdx.x, w = tid >> 6, lane = tid & 63;
  bool qpref = (qn < C_SP);
  float vals[4];
  float mx = -3.0e38f;
  #pragma unroll
  for (int j = 0; j < 4; ++j){
    int col = tid + j*256;
    float v = -3.0e38f;
    if (col < C_N && !(qpref && col >= C_SP)) v = __bfloat162float(row[col]);
    vals[j] = v; mx = fmaxf(mx, v);
  }
  mx = wredmax(mx);
  __shared__ float red[4];
  if (lane == 0) red[w] = mx;
  __syncthreads();
  mx = fmaxf(fmaxf(red[0], red[1]), fmaxf(red[2], red[3]));
  __syncthreads();
  float sum = 0.0f;
  #pragma unroll
  for (int j = 0; j < 4; ++j){
    float e = (vals[j] > -1.0e37f) ? __expf(vals[j] - mx) : 0.0f;
    vals[j] = e; sum += e;
  }
  sum = wredsum(sum);
  if (lane == 0) red[w] = sum;
  __syncthreads();
  sum = red[0] + red[1] + red[2] + red[3];
  float invs = 1.0f / sum;
  #pragma unroll
  for (int j = 0; j < 4; ++j){
    int col = tid + j*256;
    if (col < C_N) row[col] = __float2bfloat16(vals[j] * invs);
    else if (col < C_NP) row[col] = __float2bfloat16(0.0f);
  }
}

// ---------------- generic 128x128 bf16 MFMA GEMM (kept for ragged/small shapes) -------
enum { M_F32 = 0, M_SBF16 = 1, M_ATTN_O = 2, M_RES_P = 3, M_RES_S = 4, M_OUT_P = 5, M_OUT_S = 6 };

template<int MODE>
__global__ __launch_bounds__(256, 2)
void gemm128(int nmt, int nnt,
             const bf16* __restrict__ Ab, long sA, int Ma,
             const bf16* __restrict__ Wb, long sW, int Nw,
             int K,
             void* __restrict__ Cb, long sC, int ldC, int Mc, int Nc,
             const float* __restrict__ aux0, long sAux0,
             const float* __restrict__ aux1,
             float scale)
{
  __shared__ bf16 As[128*32];
  __shared__ bf16 Bs[128*32];
  const int tid = threadIdx.x;
  const int w = tid >> 6, lane = tid & 63;
  const int wr = w >> 1, wc = w & 1;
  const int z = blockIdx.z;
  int tmi, tni;
  tile_swizzle(blockIdx.x, nmt, nnt, tmi, tni);
  const int tm = tmi * 128, tn = tni * 128;
  const bf16* A = Ab + (long)z * sA;
  const bf16* W = Wb + (long)z * sW;

  f32x4 acc[4][4] = {};

  const int r0 = tid >> 2;
  const int cb = (tid & 3) * 8;
  int ar0 = tm + r0;       if (ar0 >= Ma) ar0 = Ma - 1;
  int ar1 = tm + r0 + 64;  if (ar1 >= Ma) ar1 = Ma - 1;
  int nr0 = tn + r0;       if (nr0 >= Nw) nr0 = Nw - 1;
  int nr1 = tn + r0 + 64;  if (nr1 >= Nw) nr1 = Nw - 1;
  const bf16* ga0 = A + (long)ar0 * K + cb;
  const bf16* ga1 = A + (long)ar1 * K + cb;
  const bf16* gw0 = W + (long)nr0 * K + cb;
  const bf16* gw1 = W + (long)nr1 * K + cb;
  bf16* lA0 = As + tid * 8;
  bf16* lA1 = As + (tid + 256) * 8;
  bf16* lB0 = Bs + tid * 8;
  bf16* lB1 = Bs + (tid + 256) * 8;

  const int a_off = (wr*64 + (lane & 15)) * 32 + (lane >> 4) * 8;
  const int b_off = (wc*64 + (lane & 15)) * 32 + (lane >> 4) * 8;

  for (int kt = 0; kt < K; kt += 32){
    GLD_LDS16(ga0, lA0); GLD_LDS16(ga1, lA1);
    GLD_LDS16(gw0, lB0); GLD_LDS16(gw1, lB1);
    ga0 += 32; ga1 += 32; gw0 += 32; gw1 += 32;
    __syncthreads();
    bf16x8 af[4], bfr[4];
    #pragma unroll
    for (int r = 0; r < 4; ++r) af[r]  = *(const bf16x8*)(As + a_off + r*512);
    #pragma unroll
    for (int c = 0; c < 4; ++c) bfr[c] = *(const bf16x8*)(Bs + b_off + c*512);
    #pragma unroll
    for (int r = 0; r < 4; ++r)
      #pragma unroll
      for (int c = 0; c < 4; ++c)
        acc[r][c] = MFMA16(af[r], bfr[c], acc[r][c]);
    __syncthreads();
  }

  #pragma unroll
  for (int r = 0; r < 4; ++r){
    #pragma unroll
    for (int c = 0; c < 4; ++c){
      #pragma unroll
      for (int i = 0; i < 4; ++i){
        int row = tm + wr*64 + r*16 + (lane >> 4)*4 + i;
        int col = tn + wc*64 + c*16 + (lane & 15);
        if (row >= Mc || col >= Nc) continue;
        float v = acc[r][c][i];
        if constexpr (MODE == M_F32) {
          ((float*)Cb + (long)z*sC)[(long)row*ldC + col] = v;
        } else if constexpr (MODE == M_SBF16) {
          ((bf16*)Cb + (long)z*sC)[(long)row*ldC + col] = __float2bfloat16(v * scale);
        } else if constexpr (MODE == M_ATTN_O) {
          int h = row / C_N, qn = row - h*C_N;
          ((bf16*)Cb + (long)z*sC)[(long)qn*(C_H*C_HD) + h*C_HD + col] = __float2bfloat16(v);
        } else if constexpr (MODE == M_RES_P) {
          const float* X = aux0 + (long)z*sAux0;
          ((float*)Cb + (long)z*sC)[(long)row*ldC + col] = X[(long)row*ldC + col] + v;
        } else if constexpr (MODE == M_RES_S) {
          const float* X = aux0 + (long)z*sAux0;
          float g = aux1[z*3072 + 2048 + col];
          ((float*)Cb + (long)z*sC)[(long)row*ldC + col] = X[(long)row*ldC + col] + v * g;
        } else if constexpr (MODE == M_OUT_P) {
          ((float*)Cb)[(long)row*ldC + col] = aux0[(long)row*ldC + col] + v;
        } else if constexpr (MODE == M_OUT_S) {
          int bb = row / C_SS;
          ((float*)Cb)[(long)row*ldC + col] =
              aux0[(long)row*ldC + col] + v * aux1[bb*3072 + 2048 + col];
        }
      }
    }
  }
}

// ---------------- fused gate/up GEMM (suffix only now) ----------------
__global__ __launch_bounds__(256, 2)
void gemm_gateup(int nmt, int nnt,
                 const bf16* __restrict__ A, const bf16* __restrict__ Wg,
                 const bf16* __restrict__ Wu, int N, int K, bf16* __restrict__ act)
{
  __shared__ bf16 As[128*32];
  __shared__ bf16 Bg[64*32];
  __shared__ bf16 Bu[64*32];
  const int tid = threadIdx.x;
  const int w = tid >> 6, lane = tid & 63;
  const int wr = w >> 1, wc = w & 1;
  int tmi, tni;
  tile_swizzle(blockIdx.x, nmt, nnt, tmi, tni);
  const long tm = (long)tmi * 128;
  const int tn = tni * 64;

  f32x4 ag[4][2] = {}, au[4][2] = {};

  const int r0 = tid >> 2;
  const int cb = (tid & 3) * 8;
  const bf16* gA0 = A + (tm + r0) * K + cb;
  const bf16* gA1 = gA0 + (long)64 * K;
  const bf16* gG  = Wg + ((long)tn + r0) * K + cb;
  const bf16* gU  = Wu + ((long)tn + r0) * K + cb;
  bf16* lA0 = As + tid * 8;
  bf16* lA1 = As + (tid + 256) * 8;
  bf16* lG  = Bg + tid * 8;
  bf16* lU  = Bu + tid * 8;

  const int a_off = (wr*64 + (lane & 15)) * 32 + (lane >> 4) * 8;
  const int b_off = (wc*32 + (lane & 15)) * 32 + (lane >> 4) * 8;

  for (int kt = 0; kt < K; kt += 32){
    GLD_LDS16(gA0, lA0); GLD_LDS16(gA1, lA1);
    GLD_LDS16(gG, lG);   GLD_LDS16(gU, lU);
    gA0 += 32; gA1 += 32; gG += 32; gU += 32;
    __syncthreads();
    bf16x8 af[4], bg[2], bu[2];
    #pragma unroll
    for (int r = 0; r < 4; ++r) af[r] = *(const bf16x8*)(As + a_off + r*512);
    #pragma unroll
    for (int c = 0; c < 2; ++c){
      bg[c] = *(const bf16x8*)(Bg + b_off + c*512);
      bu[c] = *(const bf16x8*)(Bu + b_off + c*512);
    }
    #pragma unroll
    for (int r = 0; r < 4; ++r)
      #pragma unroll
      for (int c = 0; c < 2; ++c){
        ag[r][c] = MFMA16(af[r], bg[c], ag[r][c]);
        au[r][c] = MFMA16(af[r], bu[c], au[r][c]);
      }
    __syncthreads();
  }

  #pragma unroll
  for (int r = 0; r < 4; ++r)
    #pragma unroll
    for (int c = 0; c < 2; ++c)
      #pragma unroll
      for (int i = 0; i < 4; ++i){
        long row = tm + wr*64 + r*16 + (lane >> 4)*4 + i;
        int col = tn + wc*32 + c*16 + (lane & 15);
        float g = ag[r][c][i], u = au[r][c][i];
        float t = tanhf(0.7978845608f * (g + 0.044715f * g*g*g));
        act[row * N + col] = __float2bfloat16(0.5f * g * (1.0f + t) * u);
      }
}

// =====================================================================================
// 256x256 8-phase pipelined GEMM (T2 st_16x32 swizzle + T3/T4 counted vmcnt + T5 setprio)
// A [M,K] bf16 row-major, W [N,K] bf16 (B = W^T). M % 256 == 0, K % 64 == 0.
// Dense: N-tile 256 (W0==W1, B0 rows tn..tn+127, B1 rows tn+128..tn+255).
// GU:    N-tile 128 (B0 = Wg rows tn..tn+127, B1 = Wu rows tn..tn+127), fused act epilogue.
// Schedule: per K-tile (BK=64) 4 phases; per-tile stage order sigma = [A0,B1,A1,B0];
// staging leads compute by 7 half-tiles -> vmcnt(6) once per K-tile (0 at last boundary).
// =====================================================================================
enum { G_F32 = 0, G_OUT = 1, G_GU = 2 };

#define G256_LDA(mh) \
  _Pragma("unroll") for (int mf = 0; mf < 4; ++mf) \
  _Pragma("unroll") for (int ks = 0; ks < 2; ++ks) \
    aF[mf][ks] = *(const bf16x8*)(smem + D + (mh)*16384 + aoff + mf*2048 + ks*64);

#define G256_LDB(nh) \
  _Pragma("unroll") for (int nf = 0; nf < 2; ++nf) \
  _Pragma("unroll") for (int ks = 0; ks < 2; ++ks) \
    bF[nf][ks] = *(const bf16x8*)(smem + D + 32768 + (nh)*16384 + boff + nf*2048 + ks*64);

#define G256_MM(mh, nh) \
  __builtin_amdgcn_s_setprio(1); \
  _Pragma("unroll") for (int mf = 0; mf < 4; ++mf) \
  _Pragma("unroll") for (int nf = 0; nf < 2; ++nf) \
  _Pragma("unroll") for (int ks = 0; ks < 2; ++ks) \
    acc[mh][mf][nh][nf] = MFMA16(aF[mf][ks], bF[nf][ks], acc[mh][mf][nh][nf]); \
  __builtin_amdgcn_s_setprio(0);

#define G256_BAR __builtin_amdgcn_s_barrier()
#define G256_LGKM0 asm volatile("s_waitcnt lgkmcnt(0)" ::: "memory")

template<int MODE>
__global__ __launch_bounds__(512, 2)
void gemm256(int nmt, int nnt,
             const bf16* __restrict__ A, int K,
             const bf16* __restrict__ W0, const bf16* __restrict__ W1,
             void* __restrict__ Cb, int ldC,
             const float* __restrict__ aux0)
{
  __shared__ char smem[131072];   // 2 buf x (A:32K + B:32K)
  const int tid  = threadIdx.x;
  const int lane = tid & 63;
  const int w    = tid >> 6;
  const int wr   = w >> 2;     // 0..1
  const int wc   = w & 3;      // 0..3
  const int NKT  = K >> 6;

  int tmi, tni;
  tile_swizzle(blockIdx.x, nmt, nnt, tmi, tni);
  const int tm  = tmi * 256;
  const int tn  = (MODE == G_GU) ? tni * 128 : tni * 256;
  const int bn0 = tn;
  const int bn1 = (MODE == G_GU) ? tn : tn + 128;

  // ---- stage source addresses (pre-swizzled global src, linear LDS dest) ----
  // LDS granule g holds linear granule g ^ (((g>>5)&1)<<1)  (byte bit5 ^= bit9)
  const int r0 = tid >> 3;                                 // 0..63
  const int cg = (tid & 7) ^ (((tid >> 5) & 1) << 1);      // permuted 16B col granule
  const bf16* gA0 = A  + (size_t)(tm  + r0) * K + cg * 8;
  const bf16* gA1 = gA0 + (size_t)128 * K;
  const bf16* gB0 = W0 + (size_t)(bn0 + r0) * K + cg * 8;
  const bf16* gB1 = W1 + (size_t)(bn1 + r0) * K + cg * 8;

  auto STAGE = [&](const bf16* base, int ldsOff, int kt){
    const bf16* s = base + (size_t)kt * 64;
    char* d = smem + ldsOff + tid * 16;
    GLD_LDS16(s, d);
    GLD_LDS16(s + (size_t)64 * K, d + 8192);
  };

  // ---- ds_read fragment offsets (swizzled: byte ^= 32 when row&4) ----
  const int koffswz = ((lane >> 4) * 16) ^ ((lane & 4) << 3);
  const int aoff = (wr*64 + (lane & 15)) * 128 + koffswz;
  const int boff = (wc*32 + (lane & 15)) * 128 + koffswz;

  f32x4 acc[2][4][2][2] = {};
  bf16x8 aF[4][2], bF[2][2];

  // ---- prologue: stage tile0 fully + tile1 sigma0..2 ----
  STAGE(gA0, 0,         0);
  STAGE(gB1, 49152,     0);
  STAGE(gA1, 16384,     0);
  STAGE(gB0, 32768,     0);
  if (NKT > 1){
    STAGE(gA0, 65536 + 0,     1);
    STAGE(gB1, 65536 + 49152, 1);
    STAGE(gA1, 65536 + 16384, 1);
    asm volatile("s_waitcnt vmcnt(6)" ::: "memory");
  } else {
    asm volatile("s_waitcnt vmcnt(0)" ::: "memory");
  }
  G256_BAR;

  for (int t = 0; t < NKT; ++t){
    const int D  = (t & 1) << 16;
    const int Dn = ((t + 1) & 1) << 16;
    // phase 0: quadrant (mh0, nh0)
    G256_LDA(0); G256_LDB(0);
    if (t + 1 < NKT) STAGE(gB0, Dn + 32768, t + 1);
    G256_BAR; G256_LGKM0;
    G256_MM(0, 0);
    G256_BAR;
    // phase 1: (mh0, nh1) — aF held
    G256_LDB(1);
    if (t + 2 < NKT) STAGE(gA0, D + 0, t + 2);
    G256_BAR; G256_LGKM0;
    G256_MM(0, 1);
    G256_BAR;
    // phase 2: (mh1, nh1) — bF held
    G256_LDA(1);
    if (t + 2 < NKT) STAGE(gB1, D + 49152, t + 2);
    G256_BAR; G256_LGKM0;
    G256_MM(1, 1);
    G256_BAR;
    // phase 3: (mh1, nh0) — re-read B0
    G256_LDB(0);
    if (t + 2 < NKT) STAGE(gA1, D + 16384, t + 2);
    G256_BAR; G256_LGKM0;
    G256_MM(1, 0);
    if (t < NKT - 2)       { asm volatile("s_waitcnt vmcnt(6)" ::: "memory"); }
    else if (t == NKT - 2) { asm volatile("s_waitcnt vmcnt(0)" ::: "memory"); }
    G256_BAR;
  }

  // ---- epilogue ----
  if constexpr (MODE == G_GU) {
    bf16* act = (bf16*)Cb;
    #pragma unroll
    for (int mh = 0; mh < 2; ++mh)
      #pragma unroll
      for (int mf = 0; mf < 4; ++mf)
        #pragma unroll
        for (int nf = 0; nf < 2; ++nf)
          #pragma unroll
          for (int i = 0; i < 4; ++i){
            long row = tm + mh*128 + wr*64 + mf*16 + (lane >> 4)*4 + i;
            int  col = tn + wc*32 + nf*16 + (lane & 15);
            float g = acc[mh][mf][0][nf][i];
            float u = acc[mh][mf][1][nf][i];
            float th = tanhf(0.7978845608f * (g + 0.044715f * g*g*g));
            act[row * (long)ldC + col] = __float2bfloat16(0.5f * g * (1.0f + th) * u);
          }
  } else {
    #pragma unroll
    for (int mh = 0; mh < 2; ++mh)
      #pragma unroll
      for (int mf = 0; mf < 4; ++mf)
        #pragma unroll
        for (int nh = 0; nh < 2; ++nh)
          #pragma unroll
          for (int nf = 0; nf < 2; ++nf)
            #pragma unroll
            for (int i = 0; i < 4; ++i){
              long row = tm + mh*128 + wr*64 + mf*16 + (lane >> 4)*4 + i;
              int  col = tn + nh*128 + wc*32 + nf*16 + (lane & 15);
              long idx = row * (long)ldC + col;
              float v = acc[mh][mf][nh][nf][i];
              if constexpr (MODE == G_F32) ((float*)Cb)[idx] = v;
              else                         ((float*)Cb)[idx] = aux0[idx] + v;
            }
  }
}

// =====================================================================================
extern "C" void kernel_launch(void* const* d_in, const int* in_sizes, int n_in,
                              void* d_out, int out_size, void* d_ws, size_t ws_size,
                              hipStream_t stream)
{
  (void)in_sizes; (void)n_in; (void)out_size; (void)ws_size;
  const float* prefix_x    = (const float*)d_in[0];
  const float* suffix_x    = (const float*)d_in[1];
  const float* cond        = (const float*)d_in[2];
  const float* p_ln_w      = (const float*)d_in[3];
  const float* p_q_w       = (const float*)d_in[4];
  const float* p_k_w       = (const float*)d_in[5];
  const float* p_v_w       = (const float*)d_in[6];
  const float* p_o_w       = (const float*)d_in[7];
  const float* p_post_ln_w = (const float*)d_in[8];
  const float* p_gate_w    = (const float*)d_in[9];
  const float* p_up_w      = (const float*)d_in[10];
  const float* p_down_w    = (const float*)d_in[11];
  const float* s_ada1_w    = (const float*)d_in[12];
  const float* s_ada1_b    = (const float*)d_in[13];
  const float* s_q_w       = (const float*)d_in[14];
  const float* s_k_w       = (const float*)d_in[15];
  const float* s_v_w       = (const float*)d_in[16];
  const float* s_o_w       = (const float*)d_in[17];
  const float* s_ada2_w    = (const float*)d_in[18];
  const float* s_ada2_b    = (const float*)d_in[19];
  const float* s_gate_w    = (const float*)d_in[20];
  const float* s_up_w      = (const float*)d_in[21];
  const float* s_down_w    = (const float*)d_in[22];

  char* ws = (char*)d_ws;
  size_t off = 0;
  auto alloc = [&](size_t b){ size_t o = off; off += (b + 255) & ~(size_t)255; return o; };

  // persistent bf16 weights
  size_t oWqkv_p = alloc((size_t)2560*2048*2);
  size_t oWqkv_s = alloc((size_t)2560*1024*2);
  size_t oWo_p   = alloc((size_t)2048*2048*2);
  size_t oWo_s   = alloc((size_t)1024*2048*2);
  size_t oWg_p   = alloc((size_t)16384*2048*2);
  size_t oWu_p   = alloc((size_t)16384*2048*2);
  size_t oWd_p   = alloc((size_t)2048*16384*2);
  size_t oWg_s   = alloc((size_t)4096*1024*2);
  size_t oWu_s   = alloc((size_t)4096*1024*2);
  size_t oWd_s   = alloc((size_t)1024*4096*2);
  // persistent activations
  size_t oHp   = alloc((size_t)6400*2048*2);
  size_t oHs   = alloc((size_t)384*1024*2);
  size_t oMod1 = alloc((size_t)8*3072*4);
  size_t oMod2 = alloc((size_t)8*3072*4);
  size_t oResS = alloc((size_t)384*1024*4);
  size_t oActS = alloc((size_t)384*4096*2);
  size_t oResP = alloc((size_t)6400*2048*4);
  // BIG region (attention-phase buffers; later overlaid by act_p)
  size_t oQkvP = alloc((size_t)6400*2560*4);
  size_t oQkvS = alloc((size_t)384*2560*4);
  size_t oQr   = alloc((size_t)8*8*848*256*2);
  size_t oKr   = alloc((size_t)8*848*256*2);
  size_t oVt   = alloc((size_t)8*256*864*2);
  size_t oS    = alloc((size_t)8*6784*864*2);
  size_t oO    = alloc((size_t)8*848*2048*2);
  size_t oActP = oQkvP;  // overlay: 209.7MB fits in attention-phase region

  // 1. convert all weights -> bf16, single launch
  {
    ConvTab t;
    struct { const float* s; size_t d; long n; } segs[14] = {
      {p_q_w,    oWqkv_p,                       (long)2048*2048},
      {p_k_w,    oWqkv_p + (size_t)2048*2048*2, (long)256*2048},
      {p_v_w,    oWqkv_p + (size_t)2304*2048*2, (long)256*2048},
      {s_q_w,    oWqkv_s,                       (long)2048*1024},
      {s_k_w,    oWqkv_s + (size_t)2048*1024*2, (long)256*1024},
      {s_v_w,    oWqkv_s + (size_t)2304*1024*2, (long)256*1024},
      {p_o_w,    oWo_p,   (long)2048*2048},
      {s_o_w,    oWo_s,   (long)1024*2048},
      {p_gate_w, oWg_p,   (long)16384*2048},
      {p_up_w,   oWu_p,   (long)16384*2048},
      {p_down_w, oWd_p,   (long)2048*16384},
      {s_gate_w, oWg_s,   (long)4096*1024},
      {s_up_w,   oWu_s,   (long)4096*1024},
      {s_down_w, oWd_s,   (long)1024*4096},
    };
    int c = 0;
    for (int i = 0; i < 14; ++i){
      t.src[i] = segs[i].s;
      t.dst[i] = (bf16*)(ws + segs[i].d);
      t.cum[i] = c;
      c += (int)(segs[i].n / 2048);
    }
    t.cum[14] = c;
    convert_all_k<<<c, 256, 0, stream>>>(t);
  }

  // 2. pre-norms
  gemma_norm_k<<<6400, 256, 0, stream>>>(prefix_x, p_ln_w, (bf16*)(ws + oHp));
  ada_mod_k<<<24, 256, 0, stream>>>(cond, s_ada1_w, s_ada1_b, s_ada2_w, s_ada2_b,
                                    (float*)(ws + oMod1), (float*)(ws + oMod2));
  ada_norm_k<<<384, 256, 0, stream>>>(suffix_x, (const float*)(ws + oMod1), (bf16*)(ws + oHs));

  // 3. qkv projections (fp32 out)
  gemm256<G_F32><<<dim3(25*10,1,1), 512, 0, stream>>>(25, 10,
      (const bf16*)(ws+oHp), 2048,
      (const bf16*)(ws+oWqkv_p), (const bf16*)(ws+oWqkv_p),
      ws+oQkvP, 2560, nullptr);
  gemm128<M_F32><<<dim3(3*20,1,1), 256, 0, stream>>>(3, 20,
      (const bf16*)(ws+oHs), 0, 384, (const bf16*)(ws+oWqkv_s), 0, 2560, 1024,
      ws+oQkvS, 0, 2560, 384, 2560, nullptr, 0, nullptr, 1.0f);

  // 4. RoPE + scatter
  rope_k<<<8*848, 256, 0, stream>>>((const float*)(ws+oQkvP), (const float*)(ws+oQkvS),
                                    (bf16*)(ws+oQr), (bf16*)(ws+oKr), (bf16*)(ws+oVt));

  // 5. S = QK^T * 1/16
  gemm128<M_SBF16><<<dim3(53*7,1,8), 256, 0, stream>>>(53, 7,
      (const bf16*)(ws+oQr), (long)6784*256, 6784,
      (const bf16*)(ws+oKr), (long)848*256, 848, 256,
      ws+oS, (long)6784*864, 864, 6784, 848, nullptr, 0, nullptr, 0.0625f);

  // 6. masked softmax
  softmax_k<<<dim3(6784,8), 256, 0, stream>>>((bf16*)(ws+oS));

  // 7. O = P @ V
  gemm128<M_ATTN_O><<<dim3(53*2,1,8), 256, 0, stream>>>(53, 2,
      (const bf16*)(ws+oS), (long)6784*864, 6784,
      (const bf16*)(ws+oVt), (long)256*864, 256, 864,
      ws+oO, (long)848*2048, 2048, 6784, 256, nullptr, 0, nullptr, 1.0f);

  // 8. o-projections + residuals
  gemm128<M_RES_P><<<dim3(7*16,1,8), 256, 0, stream>>>(7, 16,
      (const bf16*)(ws+oO), (long)848*2048, 800,
      (const bf16*)(ws+oWo_p), 0, 2048, 2048,
      ws+oResP, (long)800*2048, 2048, 800, 2048, prefix_x, (long)800*2048, nullptr, 1.0f);
  gemm128<M_RES_S><<<dim3(1*8,1,8), 256, 0, stream>>>(1, 8,
      (const bf16*)(ws+oO) + (long)800*2048, (long)848*2048, 48,
      (const bf16*)(ws+oWo_s), 0, 1024, 2048,
      ws+oResS, (long)48*1024, 1024, 48, 1024, suffix_x, (long)48*1024,
      (const float*)(ws+oMod1), 1.0f);

  // 9. post-norms
  gemma_norm_k<<<6400, 256, 0, stream>>>((const float*)(ws+oResP), p_post_ln_w, (bf16*)(ws+oHp));
  ada_norm_k<<<384, 256, 0, stream>>>((const float*)(ws+oResS), (const float*)(ws+oMod2),
                                      (bf16*)(ws+oHs));

  // 10. MLPs
  gemm256<G_GU><<<dim3(25*128,1,1), 512, 0, stream>>>(25, 128,
      (const bf16*)(ws+oHp), 2048,
      (const bf16*)(ws+oWg_p), (const bf16*)(ws+oWu_p),
      ws+oActP, 16384, nullptr);
  gemm256<G_OUT><<<dim3(25*8,1,1), 512, 0, stream>>>(25, 8,
      (const bf16*)(ws+oActP), 16384,
      (const bf16*)(ws+oWd_p), (const bf16*)(ws+oWd_p),
      d_out, 2048, (const float*)(ws+oResP));

  gemm_gateup<<<dim3(3*64,1,1), 256, 0, stream>>>(3, 64,
      (const bf16*)(ws+oHs), (const bf16*)(ws+oWg_s), (const bf16*)(ws+oWu_s),
      4096, 1024, (bf16*)(ws+oActS));
  gemm128<M_OUT_S><<<dim3(3*8,1,1), 256, 0, stream>>>(3, 8,
      (const bf16*)(ws+oActS), 0, 384, (const bf16*)(ws+oWd_s), 0, 1024, 4096,
      (float*)d_out + (size_t)6400*2048, 0, 1024, 384, 1024,
      (const float*)(ws+oResS), 0, (const float*)(ws+oMod2), 1.0f);
}

// Round 2
// 2645.749 us; speedup vs baseline: 1.0760x; 1.0106x over previous
//
#include <hip/hip_runtime.h>
#include <hip/hip_bf16.h>
#include <cmath>

using bf16 = __hip_bfloat16;
typedef short bf16x8 __attribute__((ext_vector_type(8)));
typedef float f32x4 __attribute__((ext_vector_type(4)));

#define GLD_LDS16(g, l) __builtin_amdgcn_global_load_lds( \
    (const __attribute__((address_space(1))) void*)(g),   \
    (__attribute__((address_space(3))) void*)(l), 16, 0, 0)

#define MFMA16(a,b,c) __builtin_amdgcn_mfma_f32_16x16x32_bf16((a),(b),(c),0,0,0)

// problem constants
#define C_SP 800
#define C_SS 48
#define C_B  8
#define C_N  848      // SP+SS
#define C_NP 864      // padded to 27*32
#define C_DP 2048
#define C_DS 1024
#define C_H  8
#define C_HD 256
#define C_FP 16384
#define C_FS 4096

__device__ inline float wredsum(float v){
  #pragma unroll
  for (int o = 32; o > 0; o >>= 1) v += __shfl_down(v, o, 64);
  return v;
}
__device__ inline float wredmax(float v){
  #pragma unroll
  for (int o = 32; o > 0; o >>= 1) v = fmaxf(v, __shfl_down(v, o, 64));
  return v;
}

// Two-level locality swizzle
__device__ inline void tile_swizzle(int lin, int nmt, int nnt, int& tm, int& tn){
  int total = nmt * nnt;
  int t;
  if ((total & 7) == 0) t = (lin & 7) * (total >> 3) + (lin >> 3);
  else t = lin;
  const int GN = 8;
  int band = GN * nmt;
  int g = t / band;
  int n0 = g * GN;
  int gw = nnt - n0; if (gw > GN) gw = GN;
  int r = t - g * band;
  tm = r / gw;
  tn = n0 + r % gw;
}

// ---------------- fused fp32 -> bf16 weight conversion (single launch) ----------------
struct ConvTab {
  const float* src[14];
  bf16* dst[14];
  int cum[15];   // cumulative block counts; each block = 2048 elements
};
__global__ void convert_all_k(ConvTab t){
  int b = blockIdx.x;
  int s = 0;
  #pragma unroll 1
  while (b >= t.cum[s+1]) ++s;
  long i = ((long)(b - t.cum[s]) * 256 + threadIdx.x) * 8;
  const float* src = t.src[s] + i;
  float4 v0 = *(const float4*)(src);
  float4 v1 = *(const float4*)(src + 4);
  bf16 o[8];
  o[0]=__float2bfloat16(v0.x); o[1]=__float2bfloat16(v0.y);
  o[2]=__float2bfloat16(v0.z); o[3]=__float2bfloat16(v0.w);
  o[4]=__float2bfloat16(v1.x); o[5]=__float2bfloat16(v1.y);
  o[6]=__float2bfloat16(v1.z); o[7]=__float2bfloat16(v1.w);
  *(int4*)(t.dst[s] + i) = *(const int4*)o;
}

// ---------------- gemma RMS norm (D=2048) -> bf16 ----------------
__global__ void gemma_norm_k(const float* __restrict__ x, const float* __restrict__ w,
                             bf16* __restrict__ out){
  int row = blockIdx.x;
  int tid = threadIdx.x;
  const float* xr = x + (long)row * C_DP;
  float4 v0 = *(const float4*)(xr + tid*4);
  float4 v1 = *(const float4*)(xr + 1024 + tid*4);
  float ss = v0.x*v0.x + v0.y*v0.y + v0.z*v0.z + v0.w*v0.w
           + v1.x*v1.x + v1.y*v1.y + v1.z*v1.z + v1.w*v1.w;
  ss = wredsum(ss);
  __shared__ float red[4];
  if ((tid & 63) == 0) red[tid >> 6] = ss;
  __syncthreads();
  float tot = red[0] + red[1] + red[2] + red[3];
  float rs = rsqrtf(tot * (1.0f/2048.0f) + 1e-6f);
  bf16* orow = out + (long)row * C_DP;
  const float* wv = w;
  #pragma unroll
  for (int j = 0; j < 4; ++j){
    int c0 = tid*4 + j;
    orow[c0]        = __float2bfloat16(((&v0.x)[j]) * rs * (1.0f + wv[c0]));
    orow[c0 + 1024] = __float2bfloat16(((&v1.x)[j]) * rs * (1.0f + wv[c0 + 1024]));
  }
}

// ---------------- ada modulation: mod = cond @ w^T + b (both layers) ----------------
__global__ void ada_mod_k(const float* __restrict__ cond,
                          const float* __restrict__ w1, const float* __restrict__ b1,
                          const float* __restrict__ w2, const float* __restrict__ b2,
                          float* __restrict__ mod1, float* __restrict__ mod2){
  int idx = blockIdx.x * 256 + threadIdx.x;   // 2*3072 outputs
  int sel = idx / 3072, col = idx - sel * 3072;
  const float* w = (sel ? w2 : w1) + (long)col * C_DS;
  float acc[8] = {0,0,0,0,0,0,0,0};
  for (int k = 0; k < C_DS; k += 4){
    float4 wv = *(const float4*)(w + k);
    #pragma unroll
    for (int b = 0; b < 8; ++b){
      float4 cv = *(const float4*)(cond + b*C_DS + k);
      acc[b] += wv.x*cv.x + wv.y*cv.y + wv.z*cv.z + wv.w*cv.w;
    }
  }
  float bias = (sel ? b2 : b1)[col];
  float* m = sel ? mod2 : mod1;
  #pragma unroll
  for (int b = 0; b < 8; ++b) m[b*3072 + col] = acc[b] + bias;
}

// ---------------- ada norm (D=1024): rms(x)*(1+scale)+shift -> bf16 ----------------
__global__ void ada_norm_k(const float* __restrict__ x, const float* __restrict__ mod,
                           bf16* __restrict__ out){
  int row = blockIdx.x;       // 0..383
  int b = row / C_SS;
  int tid = threadIdx.x;
  const float* xr = x + (long)row * C_DS;
  float4 v = *(const float4*)(xr + tid*4);
  float ss = v.x*v.x + v.y*v.y + v.z*v.z + v.w*v.w;
  ss = wredsum(ss);
  __shared__ float red[4];
  if ((tid & 63) == 0) red[tid >> 6] = ss;
  __syncthreads();
  float tot = red[0] + red[1] + red[2] + red[3];
  float rs = rsqrtf(tot * (1.0f/1024.0f) + 1e-6f);
  const float* mrow = mod + (long)b * 3072;
  bf16* orow = out + (long)row * C_DS;
  #pragma unroll
  for (int j = 0; j < 4; ++j){
    int col = tid*4 + j;
    float val = ((&v.x)[j]) * rs * (1.0f + mrow[col]) + mrow[1024 + col];
    orow[col] = __float2bfloat16(val);
  }
}

// ---------------- RoPE + layout scatter ----------------
__global__ void rope_k(const float* __restrict__ qkv_p, const float* __restrict__ qkv_s,
                       bf16* __restrict__ q_r, bf16* __restrict__ k_r, bf16* __restrict__ v_t){
  int bn = blockIdx.x;
  int b = bn / C_N, n = bn - b * C_N;
  int d = threadIdx.x;  // 0..255
  const float* src = (n < C_SP) ? (qkv_p + ((long)b*C_SP + n) * 2560)
                                : (qkv_s + ((long)b*C_SS + (n - C_SP)) * 2560);
  int i = d & 127;
  float inv = expf(-(float)i * (9.210340371976184f / 128.0f)); // 1/10000^(i/128)
  float fr = (float)n * inv;
  float sn, cs;
  sincosf(fr, &sn, &cs);
  bool lo = d < 128;
  int dpair = lo ? d + 128 : d - 128;
  #pragma unroll
  for (int h = 0; h < C_H; ++h){
    float a = src[h*C_HD + d], o = src[h*C_HD + dpair];
    float r = lo ? (a*cs - o*sn) : (a*cs + o*sn);
    q_r[(((long)b*C_H + h)*C_N + n)*C_HD + d] = __float2bfloat16(r);
  }
  {
    float a = src[2048 + d], o = src[2048 + dpair];
    float r = lo ? (a*cs - o*sn) : (a*cs + o*sn);
    k_r[((long)b*C_N + n)*C_HD + d] = __float2bfloat16(r);
  }
  v_t[((long)b*C_HD + d)*C_NP + n] = __float2bfloat16(src[2304 + d]);
  if (n < C_NP - C_N)   // zero K-padding columns 848..863
    v_t[((long)b*C_HD + d)*C_NP + C_N + n] = __float2bfloat16(0.0f);
}

// ---------------- masked softmax over S rows (bf16 in/out, fp32 math) ----------------
__global__ void softmax_k(bf16* __restrict__ S){
  int m = blockIdx.x;        // 0..6783 (= h*848 + qn)
  int b = blockIdx.y;
  int qn = m % C_N;
  bf16* row = S + ((long)b * (C_H*C_N) + m) * C_NP;
  int tid = threadIdx.x, w = tid >> 6, lane = tid & 63;
  bool qpref = (qn < C_SP);
  float vals[4];
  float mx = -3.0e38f;
  #pragma unroll
  for (int j = 0; j < 4; ++j){
    int col = tid + j*256;
    float v = -3.0e38f;
    if (col < C_N && !(qpref && col >= C_SP)) v = __bfloat162float(row[col]);
    vals[j] = v; mx = fmaxf(mx, v);
  }
  mx = wredmax(mx);
  __shared__ float red[4];
  if (lane == 0) red[w] = mx;
  __syncthreads();
  mx = fmaxf(fmaxf(red[0], red[1]), fmaxf(red[2], red[3]));
  __syncthreads();
  float sum = 0.0f;
  #pragma unroll
  for (int j = 0; j < 4; ++j){
    float e = (vals[j] > -1.0e37f) ? __expf(vals[j] - mx) : 0.0f;
    vals[j] = e; sum += e;
  }
  sum = wredsum(sum);
  if (lane == 0) red[w] = sum;
  __syncthreads();
  sum = red[0] + red[1] + red[2] + red[3];
  float invs = 1.0f / sum;
  #pragma unroll
  for (int j = 0; j < 4; ++j){
    int col = tid + j*256;
    if (col < C_N) row[col] = __float2bfloat16(vals[j] * invs);
    else if (col < C_NP) row[col] = __float2bfloat16(0.0f);
  }
}

// ---------------- generic 128x128 bf16 MFMA GEMM (ragged/small shapes) ----------------
// LDS rows are 64B (32 bf16): XOR-swizzle byte bits {4,5} with row bits {1,2}
// (write side: permute source k-granule; read side: permute LDS k-granule).
enum { M_F32 = 0, M_SBF16 = 1, M_ATTN_O = 2, M_RES_P = 3, M_RES_S = 4, M_OUT_P = 5, M_OUT_S = 6 };

template<int MODE>
__global__ __launch_bounds__(256, 2)
void gemm128(int nmt, int nnt,
             const bf16* __restrict__ Ab, long sA, int Ma,
             const bf16* __restrict__ Wb, long sW, int Nw,
             int K,
             void* __restrict__ Cb, long sC, int ldC, int Mc, int Nc,
             const float* __restrict__ aux0, long sAux0,
             const float* __restrict__ aux1,
             float scale)
{
  __shared__ bf16 As[128*32];
  __shared__ bf16 Bs[128*32];
  const int tid = threadIdx.x;
  const int w = tid >> 6, lane = tid & 63;
  const int wr = w >> 1, wc = w & 1;
  const int z = blockIdx.z;
  int tmi, tni;
  tile_swizzle(blockIdx.x, nmt, nnt, tmi, tni);
  const int tm = tmi * 128, tn = tni * 128;
  const bf16* A = Ab + (long)z * sA;
  const bf16* W = Wb + (long)z * sW;

  f32x4 acc[4][4] = {};

  const int r0 = tid >> 2;
  // write-side swizzle: source granule = (tid&3) ^ (row bits 1,2) ; row = tid>>2
  const int cb = (((tid & 3) ^ ((tid >> 3) & 3)) * 8);
  int ar0 = tm + r0;       if (ar0 >= Ma) ar0 = Ma - 1;
  int ar1 = tm + r0 + 64;  if (ar1 >= Ma) ar1 = Ma - 1;
  int nr0 = tn + r0;       if (nr0 >= Nw) nr0 = Nw - 1;
  int nr1 = tn + r0 + 64;  if (nr1 >= Nw) nr1 = Nw - 1;
  const bf16* ga0 = A + (long)ar0 * K + cb;
  const bf16* ga1 = A + (long)ar1 * K + cb;
  const bf16* gw0 = W + (long)nr0 * K + cb;
  const bf16* gw1 = W + (long)nr1 * K + cb;
  bf16* lA0 = As + tid * 8;
  bf16* lA1 = As + (tid + 256) * 8;
  bf16* lB0 = Bs + tid * 8;
  bf16* lB1 = Bs + (tid + 256) * 8;

  // read-side swizzle: LDS granule = kg ^ (row bits 1,2); row bits 1,2 = lane bits 1,2
  const int kswz = (((lane >> 4) ^ ((lane >> 1) & 3)) << 3);
  const int a_off = (wr*64 + (lane & 15)) * 32 + kswz;
  const int b_off = (wc*64 + (lane & 15)) * 32 + kswz;

  for (int kt = 0; kt < K; kt += 32){
    GLD_LDS16(ga0, lA0); GLD_LDS16(ga1, lA1);
    GLD_LDS16(gw0, lB0); GLD_LDS16(gw1, lB1);
    ga0 += 32; ga1 += 32; gw0 += 32; gw1 += 32;
    __syncthreads();
    bf16x8 af[4], bfr[4];
    #pragma unroll
    for (int r = 0; r < 4; ++r) af[r]  = *(const bf16x8*)(As + a_off + r*512);
    #pragma unroll
    for (int c = 0; c < 4; ++c) bfr[c] = *(const bf16x8*)(Bs + b_off + c*512);
    #pragma unroll
    for (int r = 0; r < 4; ++r)
      #pragma unroll
      for (int c = 0; c < 4; ++c)
        acc[r][c] = MFMA16(af[r], bfr[c], acc[r][c]);
    __syncthreads();
  }

  #pragma unroll
  for (int r = 0; r < 4; ++r){
    #pragma unroll
    for (int c = 0; c < 4; ++c){
      #pragma unroll
      for (int i = 0; i < 4; ++i){
        int row = tm + wr*64 + r*16 + (lane >> 4)*4 + i;
        int col = tn + wc*64 + c*16 + (lane & 15);
        if (row >= Mc || col >= Nc) continue;
        float v = acc[r][c][i];
        if constexpr (MODE == M_F32) {
          ((float*)Cb + (long)z*sC)[(long)row*ldC + col] = v;
        } else if constexpr (MODE == M_SBF16) {
          ((bf16*)Cb + (long)z*sC)[(long)row*ldC + col] = __float2bfloat16(v * scale);
        } else if constexpr (MODE == M_ATTN_O) {
          int h = row / C_N, qn = row - h*C_N;
          ((bf16*)Cb + (long)z*sC)[(long)qn*(C_H*C_HD) + h*C_HD + col] = __float2bfloat16(v);
        } else if constexpr (MODE == M_RES_P) {
          const float* X = aux0 + (long)z*sAux0;
          ((float*)Cb + (long)z*sC)[(long)row*ldC + col] = X[(long)row*ldC + col] + v;
        } else if constexpr (MODE == M_RES_S) {
          const float* X = aux0 + (long)z*sAux0;
          float g = aux1[z*3072 + 2048 + col];
          ((float*)Cb + (long)z*sC)[(long)row*ldC + col] = X[(long)row*ldC + col] + v * g;
        } else if constexpr (MODE == M_OUT_P) {
          ((float*)Cb)[(long)row*ldC + col] = aux0[(long)row*ldC + col] + v;
        } else if constexpr (MODE == M_OUT_S) {
          int bb = row / C_SS;
          ((float*)Cb)[(long)row*ldC + col] =
              aux0[(long)row*ldC + col] + v * aux1[bb*3072 + 2048 + col];
        }
      }
    }
  }
}

// ---------------- fused gate/up GEMM (suffix only) ----------------
__global__ __launch_bounds__(256, 2)
void gemm_gateup(int nmt, int nnt,
                 const bf16* __restrict__ A, const bf16* __restrict__ Wg,
                 const bf16* __restrict__ Wu, int N, int K, bf16* __restrict__ act)
{
  __shared__ bf16 As[128*32];
  __shared__ bf16 Bg[64*32];
  __shared__ bf16 Bu[64*32];
  const int tid = threadIdx.x;
  const int w = tid >> 6, lane = tid & 63;
  const int wr = w >> 1, wc = w & 1;
  int tmi, tni;
  tile_swizzle(blockIdx.x, nmt, nnt, tmi, tni);
  const long tm = (long)tmi * 128;
  const int tn = tni * 64;

  f32x4 ag[4][2] = {}, au[4][2] = {};

  const int r0 = tid >> 2;
  const int cb = (((tid & 3) ^ ((tid >> 3) & 3)) * 8);
  const bf16* gA0 = A + (tm + r0) * K + cb;
  const bf16* gA1 = gA0 + (long)64 * K;
  const bf16* gG  = Wg + ((long)tn + r0) * K + cb;
  const bf16* gU  = Wu + ((long)tn + r0) * K + cb;
  bf16* lA0 = As + tid * 8;
  bf16* lA1 = As + (tid + 256) * 8;
  bf16* lG  = Bg + tid * 8;
  bf16* lU  = Bu + tid * 8;

  const int kswz = (((lane >> 4) ^ ((lane >> 1) & 3)) << 3);
  const int a_off = (wr*64 + (lane & 15)) * 32 + kswz;
  const int b_off = (wc*32 + (lane & 15)) * 32 + kswz;

  for (int kt = 0; kt < K; kt += 32){
    GLD_LDS16(gA0, lA0); GLD_LDS16(gA1, lA1);
    GLD_LDS16(gG, lG);   GLD_LDS16(gU, lU);
    gA0 += 32; gA1 += 32; gG += 32; gU += 32;
    __syncthreads();
    bf16x8 af[4], bg[2], bu[2];
    #pragma unroll
    for (int r = 0; r < 4; ++r) af[r] = *(const bf16x8*)(As + a_off + r*512);
    #pragma unroll
    for (int c = 0; c < 2; ++c){
      bg[c] = *(const bf16x8*)(Bg + b_off + c*512);
      bu[c] = *(const bf16x8*)(Bu + b_off + c*512);
    }
    #pragma unroll
    for (int r = 0; r < 4; ++r)
      #pragma unroll
      for (int c = 0; c < 2; ++c){
        ag[r][c] = MFMA16(af[r], bg[c], ag[r][c]);
        au[r][c] = MFMA16(af[r], bu[c], au[r][c]);
      }
    __syncthreads();
  }

  #pragma unroll
  for (int r = 0; r < 4; ++r)
    #pragma unroll
    for (int c = 0; c < 2; ++c)
      #pragma unroll
      for (int i = 0; i < 4; ++i){
        long row = tm + wr*64 + r*16 + (lane >> 4)*4 + i;
        int col = tn + wc*32 + c*16 + (lane & 15);
        float g = ag[r][c][i], u = au[r][c][i];
        float t = tanhf(0.7978845608f * (g + 0.044715f * g*g*g));
        act[row * N + col] = __float2bfloat16(0.5f * g * (1.0f + t) * u);
      }
}

// =====================================================================================
// 256x256 8-phase pipelined GEMM.
// LDS rows are 128B (64 bf16): 2-bit XOR swizzle — byte bits {5,6} ^= row bits {2,3}.
// Write side: linear LDS dest, source k-granule permuted; read side: same permutation.
// Phase walk (0,0)->(0,1)->(1,1)->(1,0) with B0 HELD IN REGISTERS across the tile:
// 24 ds_read_b128 per K-tile per wave (A:16, B:8), phase 3 is pure-MFMA.
// Counted vmcnt(6): per tile stages B0(t+1) [ph0], A0/B1/A1(t+2) [ph1-3].
// =====================================================================================
enum { G_F32 = 0, G_OUT = 1, G_GU = 2 };

#define G256_LDA(mh) \
  _Pragma("unroll") for (int mf = 0; mf < 4; ++mf) \
  _Pragma("unroll") for (int ks = 0; ks < 2; ++ks) \
    aF[mf][ks] = *(const bf16x8*)(smem + D + (mh)*16384 + arow + mf*2048 + kk[ks]);

#define G256_LDB(dst, nh) \
  _Pragma("unroll") for (int nf = 0; nf < 2; ++nf) \
  _Pragma("unroll") for (int ks = 0; ks < 2; ++ks) \
    dst[nf][ks] = *(const bf16x8*)(smem + D + 32768 + (nh)*16384 + brow + nf*2048 + kk[ks]);

#define G256_MM(mh, nh, bfm) \
  __builtin_amdgcn_s_setprio(1); \
  _Pragma("unroll") for (int mf = 0; mf < 4; ++mf) \
  _Pragma("unroll") for (int nf = 0; nf < 2; ++nf) \
  _Pragma("unroll") for (int ks = 0; ks < 2; ++ks) \
    acc[mh][mf][nh][nf] = MFMA16(aF[mf][ks], bfm[nf][ks], acc[mh][mf][nh][nf]); \
  __builtin_amdgcn_s_setprio(0);

#define G256_BAR __builtin_amdgcn_s_barrier()
#define G256_LGKM0 asm volatile("s_waitcnt lgkmcnt(0)" ::: "memory")

template<int MODE>
__global__ __launch_bounds__(512, 2)
void gemm256(int nmt, int nnt,
             const bf16* __restrict__ A, int K,
             const bf16* __restrict__ W0, const bf16* __restrict__ W1,
             void* __restrict__ Cb, int ldC,
             const float* __restrict__ aux0)
{
  __shared__ char smem[131072];   // 2 buf x (A:32K + B:32K)
  const int tid  = threadIdx.x;
  const int lane = tid & 63;
  const int w    = tid >> 6;
  const int wr   = w >> 2;     // 0..1
  const int wc   = w & 3;      // 0..3
  const int NKT  = K >> 6;

  int tmi, tni;
  tile_swizzle(blockIdx.x, nmt, nnt, tmi, tni);
  const int tm  = tmi * 256;
  const int tn  = (MODE == G_GU) ? tni * 128 : tni * 256;
  const int bn0 = tn;
  const int bn1 = (MODE == G_GU) ? tn : tn + 128;

  // ---- stage source addresses (pre-swizzled global src, linear LDS dest) ----
  // LDS (row r, 16B-granule g) holds global granule g ^ (((r>>2)&3)<<1)
  const int r0 = tid >> 3;                                   // 0..63
  const int cg = (tid & 7) ^ (((tid >> 5) & 3) << 1);        // permuted 16B col granule
  const bf16* gA0 = A  + (size_t)(tm  + r0) * K + cg * 8;
  const bf16* gA1 = gA0 + (size_t)128 * K;
  const bf16* gB0 = W0 + (size_t)(bn0 + r0) * K + cg * 8;
  const bf16* gB1 = W1 + (size_t)(bn1 + r0) * K + cg * 8;

  auto STAGE = [&](const bf16* base, int ldsOff, int kt){
    const bf16* s = base + (size_t)kt * 64;
    char* d = smem + ldsOff + tid * 16;
    GLD_LDS16(s, d);
    GLD_LDS16(s + (size_t)64 * K, d + 8192);
  };

  // ---- ds_read fragment offsets (byte bits {5,6} ^= row bits {2,3} = lane bits {2,3}) ----
  const int kmask = (lane & 12) << 3;
  const int kk[2] = { (((lane >> 4) << 4) + 0)  ^ kmask,
                      (((lane >> 4) << 4) + 64) ^ kmask };
  const int arow = (wr*64 + (lane & 15)) * 128;
  const int brow = (wc*32 + (lane & 15)) * 128;

  f32x4 acc[2][4][2][2] = {};
  bf16x8 aF[4][2], bF0[2][2], bF1[2][2];

  // ---- prologue: stage tile0 fully + tile1 {A0,B1,A1} (B0(1) staged in loop ph0) ----
  STAGE(gA0, 0,     0);
  STAGE(gB0, 32768, 0);
  STAGE(gB1, 49152, 0);
  STAGE(gA1, 16384, 0);
  if (NKT > 1){
    STAGE(gA0, 65536 + 0,     1);
    STAGE(gB1, 65536 + 49152, 1);
    STAGE(gA1, 65536 + 16384, 1);
    asm volatile("s_waitcnt vmcnt(6)" ::: "memory");
  } else {
    asm volatile("s_waitcnt vmcnt(0)" ::: "memory");
  }
  G256_BAR;

  for (int t = 0; t < NKT; ++t){
    const int D  = (t & 1) << 16;
    const int Dn = ((t + 1) & 1) << 16;
    // phase 0: (mh0, nh0) — read aF + bF0
    G256_LDA(0); G256_LDB(bF0, 0);
    if (t + 1 < NKT) STAGE(gB0, Dn + 32768, t + 1);
    G256_BAR; G256_LGKM0;
    G256_MM(0, 0, bF0);
    G256_BAR;
    // phase 1: (mh0, nh1) — aF held, read bF1
    G256_LDB(bF1, 1);
    if (t + 2 < NKT) STAGE(gA0, D + 0, t + 2);
    G256_BAR; G256_LGKM0;
    G256_MM(0, 1, bF1);
    G256_BAR;
    // phase 2: (mh1, nh1) — bF1 held, read aF
    G256_LDA(1);
    if (t + 2 < NKT) STAGE(gB1, D + 49152, t + 2);
    G256_BAR; G256_LGKM0;
    G256_MM(1, 1, bF1);
    G256_BAR;
    // phase 3: (mh1, nh0) — registers only (aF + bF0 held)
    if (t + 2 < NKT) STAGE(gA1, D + 16384, t + 2);
    G256_BAR;
    G256_MM(1, 0, bF0);
    if (t < NKT - 2)       { asm volatile("s_waitcnt vmcnt(6)" ::: "memory"); }
    else if (t == NKT - 2) { asm volatile("s_waitcnt vmcnt(0)" ::: "memory"); }
    G256_BAR;
  }

  // ---- epilogue ----
  if constexpr (MODE == G_GU) {
    bf16* act = (bf16*)Cb;
    #pragma unroll
    for (int mh = 0; mh < 2; ++mh)
      #pragma unroll
      for (int mf = 0; mf < 4; ++mf)
        #pragma unroll
        for (int nf = 0; nf < 2; ++nf)
          #pragma unroll
          for (int i = 0; i < 4; ++i){
            long row = tm + mh*128 + wr*64 + mf*16 + (lane >> 4)*4 + i;
            int  col = tn + wc*32 + nf*16 + (lane & 15);
            float g = acc[mh][mf][0][nf][i];
            float u = acc[mh][mf][1][nf][i];
            float th = tanhf(0.7978845608f * (g + 0.044715f * g*g*g));
            act[row * (long)ldC + col] = __float2bfloat16(0.5f * g * (1.0f + th) * u);
          }
  } else {
    #pragma unroll
    for (int mh = 0; mh < 2; ++mh)
      #pragma unroll
      for (int mf = 0; mf < 4; ++mf)
        #pragma unroll
        for (int nh = 0; nh < 2; ++nh)
          #pragma unroll
          for (int nf = 0; nf < 2; ++nf)
            #pragma unroll
            for (int i = 0; i < 4; ++i){
              long row = tm + mh*128 + wr*64 + mf*16 + (lane >> 4)*4 + i;
              int  col = tn + nh*128 + wc*32 + nf*16 + (lane & 15);
              long idx = row * (long)ldC + col;
              float v = acc[mh][mf][nh][nf][i];
              if constexpr (MODE == G_F32) ((float*)Cb)[idx] = v;
              else                         ((float*)Cb)[idx] = aux0[idx] + v;
            }
  }
}

// =====================================================================================
extern "C" void kernel_launch(void* const* d_in, const int* in_sizes, int n_in,
                              void* d_out, int out_size, void* d_ws, size_t ws_size,
                              hipStream_t stream)
{
  (void)in_sizes; (void)n_in; (void)out_size; (void)ws_size;
  const float* prefix_x    = (const float*)d_in[0];
  const float* suffix_x    = (const float*)d_in[1];
  const float* cond        = (const float*)d_in[2];
  const float* p_ln_w      = (const float*)d_in[3];
  const float* p_q_w       = (const float*)d_in[4];
  const float* p_k_w       = (const float*)d_in[5];
  const float* p_v_w       = (const float*)d_in[6];
  const float* p_o_w       = (const float*)d_in[7];
  const float* p_post_ln_w = (const float*)d_in[8];
  const float* p_gate_w    = (const float*)d_in[9];
  const float* p_up_w      = (const float*)d_in[10];
  const float* p_down_w    = (const float*)d_in[11];
  const float* s_ada1_w    = (const float*)d_in[12];
  const float* s_ada1_b    = (const float*)d_in[13];
  const float* s_q_w       = (const float*)d_in[14];
  const float* s_k_w       = (const float*)d_in[15];
  const float* s_v_w       = (const float*)d_in[16];
  const float* s_o_w       = (const float*)d_in[17];
  const float* s_ada2_w    = (const float*)d_in[18];
  const float* s_ada2_b    = (const float*)d_in[19];
  const float* s_gate_w    = (const float*)d_in[20];
  const float* s_up_w      = (const float*)d_in[21];
  const float* s_down_w    = (const float*)d_in[22];

  char* ws = (char*)d_ws;
  size_t off = 0;
  auto alloc = [&](size_t b){ size_t o = off; off += (b + 255) & ~(size_t)255; return o; };

  // persistent bf16 weights
  size_t oWqkv_p = alloc((size_t)2560*2048*2);
  size_t oWqkv_s = alloc((size_t)2560*1024*2);
  size_t oWo_p   = alloc((size_t)2048*2048*2);
  size_t oWo_s   = alloc((size_t)1024*2048*2);
  size_t oWg_p   = alloc((size_t)16384*2048*2);
  size_t oWu_p   = alloc((size_t)16384*2048*2);
  size_t oWd_p   = alloc((size_t)2048*16384*2);
  size_t oWg_s   = alloc((size_t)4096*1024*2);
  size_t oWu_s   = alloc((size_t)4096*1024*2);
  size_t oWd_s   = alloc((size_t)1024*4096*2);
  // persistent activations
  size_t oHp   = alloc((size_t)6400*2048*2);
  size_t oHs   = alloc((size_t)384*1024*2);
  size_t oMod1 = alloc((size_t)8*3072*4);
  size_t oMod2 = alloc((size_t)8*3072*4);
  size_t oResS = alloc((size_t)384*1024*4);
  size_t oActS = alloc((size_t)384*4096*2);
  size_t oResP = alloc((size_t)6400*2048*4);
  // BIG region (attention-phase buffers; later overlaid by act_p)
  size_t oQkvP = alloc((size_t)6400*2560*4);
  size_t oQkvS = alloc((size_t)384*2560*4);
  size_t oQr   = alloc((size_t)8*8*848*256*2);
  size_t oKr   = alloc((size_t)8*848*256*2);
  size_t oVt   = alloc((size_t)8*256*864*2);
  size_t oS    = alloc((size_t)8*6784*864*2);
  size_t oO    = alloc((size_t)8*848*2048*2);
  size_t oActP = oQkvP;  // overlay: 209.7MB fits in attention-phase region

  // 1. convert all weights -> bf16, single launch
  {
    ConvTab t;
    struct { const float* s; size_t d; long n; } segs[14] = {
      {p_q_w,    oWqkv_p,                       (long)2048*2048},
      {p_k_w,    oWqkv_p + (size_t)2048*2048*2, (long)256*2048},
      {p_v_w,    oWqkv_p + (size_t)2304*2048*2, (long)256*2048},
      {s_q_w,    oWqkv_s,                       (long)2048*1024},
      {s_k_w,    oWqkv_s + (size_t)2048*1024*2, (long)256*1024},
      {s_v_w,    oWqkv_s + (size_t)2304*1024*2, (long)256*1024},
      {p_o_w,    oWo_p,   (long)2048*2048},
      {s_o_w,    oWo_s,   (long)1024*2048},
      {p_gate_w, oWg_p,   (long)16384*2048},
      {p_up_w,   oWu_p,   (long)16384*2048},
      {p_down_w, oWd_p,   (long)2048*16384},
      {s_gate_w, oWg_s,   (long)4096*1024},
      {s_up_w,   oWu_s,   (long)4096*1024},
      {s_down_w, oWd_s,   (long)1024*4096},
    };
    int c = 0;
    for (int i = 0; i < 14; ++i){
      t.src[i] = segs[i].s;
      t.dst[i] = (bf16*)(ws + segs[i].d);
      t.cum[i] = c;
      c += (int)(segs[i].n / 2048);
    }
    t.cum[14] = c;
    convert_all_k<<<c, 256, 0, stream>>>(t);
  }

  // 2. pre-norms
  gemma_norm_k<<<6400, 256, 0, stream>>>(prefix_x, p_ln_w, (bf16*)(ws + oHp));
  ada_mod_k<<<24, 256, 0, stream>>>(cond, s_ada1_w, s_ada1_b, s_ada2_w, s_ada2_b,
                                    (float*)(ws + oMod1), (float*)(ws + oMod2));
  ada_norm_k<<<384, 256, 0, stream>>>(suffix_x, (const float*)(ws + oMod1), (bf16*)(ws + oHs));

  // 3. qkv projections (fp32 out)
  gemm256<G_F32><<<dim3(25*10,1,1), 512, 0, stream>>>(25, 10,
      (const bf16*)(ws+oHp), 2048,
      (const bf16*)(ws+oWqkv_p), (const bf16*)(ws+oWqkv_p),
      ws+oQkvP, 2560, nullptr);
  gemm128<M_F32><<<dim3(3*20,1,1), 256, 0, stream>>>(3, 20,
      (const bf16*)(ws+oHs), 0, 384, (const bf16*)(ws+oWqkv_s), 0, 2560, 1024,
      ws+oQkvS, 0, 2560, 384, 2560, nullptr, 0, nullptr, 1.0f);

  // 4. RoPE + scatter
  rope_k<<<8*848, 256, 0, stream>>>((const float*)(ws+oQkvP), (const float*)(ws+oQkvS),
                                    (bf16*)(ws+oQr), (bf16*)(ws+oKr), (bf16*)(ws+oVt));

  // 5. S = QK^T * 1/16
  gemm128<M_SBF16><<<dim3(53*7,1,8), 256, 0, stream>>>(53, 7,
      (const bf16*)(ws+oQr), (long)6784*256, 6784,
      (const bf16*)(ws+oKr), (long)848*256, 848, 256,
      ws+oS, (long)6784*864, 864, 6784, 848, nullptr, 0, nullptr, 0.0625f);

  // 6. masked softmax
  softmax_k<<<dim3(6784,8), 256, 0, stream>>>((bf16*)(ws+oS));

  // 7. O = P @ V
  gemm128<M_ATTN_O><<<dim3(53*2,1,8), 256, 0, stream>>>(53, 2,
      (const bf16*)(ws+oS), (long)6784*864, 6784,
      (const bf16*)(ws+oVt), (long)256*864, 256, 864,
      ws+oO, (long)848*2048, 2048, 6784, 256, nullptr, 0, nullptr, 1.0f);

  // 8. o-projections + residuals
  gemm128<M_RES_P><<<dim3(7*16,1,8), 256, 0, stream>>>(7, 16,
      (const bf16*)(ws+oO), (long)848*2048, 800,
      (const bf16*)(ws+oWo_p), 0, 2048, 2048,
      ws+oResP, (long)800*2048, 2048, 800, 2048, prefix_x, (long)800*2048, nullptr, 1.0f);
  gemm128<M_RES_S><<<dim3(1*8,1,8), 256, 0, stream>>>(1, 8,
      (const bf16*)(ws+oO) + (long)800*2048, (long)848*2048, 48,
      (const bf16*)(ws+oWo_s), 0, 1024, 2048,
      ws+oResS, (long)48*1024, 1024, 48, 1024, suffix_x, (long)48*1024,
      (const float*)(ws+oMod1), 1.0f);

  // 9. post-norms
  gemma_norm_k<<<6400, 256, 0, stream>>>((const float*)(ws+oResP), p_post_ln_w, (bf16*)(ws+oHp));
  ada_norm_k<<<384, 256, 0, stream>>>((const float*)(ws+oResS), (const float*)(ws+oMod2),
                                      (bf16*)(ws+oHs));

  // 10. MLPs
  gemm256<G_GU><<<dim3(25*128,1,1), 512, 0, stream>>>(25, 128,
      (const bf16*)(ws+oHp), 2048,
      (const bf16*)(ws+oWg_p), (const bf16*)(ws+oWu_p),
      ws+oActP, 16384, nullptr);
  gemm256<G_OUT><<<dim3(25*8,1,1), 512, 0, stream>>>(25, 8,
      (const bf16*)(ws+oActP), 16384,
      (const bf16*)(ws+oWd_p), (const bf16*)(ws+oWd_p),
      d_out, 2048, (const float*)(ws+oResP));

  gemm_gateup<<<dim3(3*64,1,1), 256, 0, stream>>>(3, 64,
      (const bf16*)(ws+oHs), (const bf16*)(ws+oWg_s), (const bf16*)(ws+oWu_s),
      4096, 1024, (bf16*)(ws+oActS));
  gemm128<M_OUT_S><<<dim3(3*8,1,1), 256, 0, stream>>>(3, 8,
      (const bf16*)(ws+oActS), 0, 384, (const bf16*)(ws+oWd_s), 0, 1024, 4096,
      (float*)d_out + (size_t)6400*2048, 0, 1024, 384, 1024,
      (const float*)(ws+oResS), 0, (const float*)(ws+oMod2), 1.0f);
}